// Round 2
// baseline (1261.640 us; speedup 1.0000x reference)
//
#include <hip/hip_runtime.h>
#include <hip/hip_bf16.h>
#include <cstdint>
#include <math.h>

typedef __attribute__((ext_vector_type(4))) float f32x4;
typedef __attribute__((ext_vector_type(8))) __bf16 bf16x8;

__device__ __forceinline__ unsigned short f2bf(float f) {
    union { float f; unsigned u; } v; v.f = f;
    unsigned u = v.u + 0x7fffu + ((v.u >> 16) & 1u);
    return (unsigned short)(u >> 16);
}

__device__ __forceinline__ float gelu_tanh(float x) {
    float x3 = x * x * x;
    float t = tanhf(0.7978845608028654f * (x + 0.044715f * x3));
    return 0.5f * x * (1.0f + t);
}

__device__ __forceinline__ void gload_lds16(const void* g, void* l) {
    __builtin_amdgcn_global_load_lds(
        (__attribute__((address_space(1))) void*)(uintptr_t)g,
        (__attribute__((address_space(3))) void*)(unsigned)(uintptr_t)l,
        16, 0, 0);
}

// ---------------- fused bias-add + residual + LayerNorm ----------------
__global__ __launch_bounds__(256)
void fused_add_ln(const float* __restrict__ in, const float* __restrict__ res,
                  const float* __restrict__ bias, const float* __restrict__ nw,
                  const float* __restrict__ nb, float* __restrict__ resadd,
                  unsigned short* __restrict__ lnout, int H) {
    const int row = blockIdx.x;
    const int tid = threadIdx.x;
    const size_t base = (size_t)row * H;
    float v[16];
    float s = 0.f, ss = 0.f;
#pragma unroll
    for (int i = 0; i < 4; ++i) {
        int idx = (i * 256 + tid) * 4;
        float4 a = *(const float4*)(in + base + idx);
        float4 b = *(const float4*)(res + base + idx);
        float4 c = *(const float4*)(bias + idx);
        float x0 = a.x + b.x + c.x, x1 = a.y + b.y + c.y;
        float x2 = a.z + b.z + c.z, x3 = a.w + b.w + c.w;
        v[i * 4 + 0] = x0; v[i * 4 + 1] = x1; v[i * 4 + 2] = x2; v[i * 4 + 3] = x3;
        s += x0 + x1 + x2 + x3;
        ss += x0 * x0 + x1 * x1 + x2 * x2 + x3 * x3;
    }
#pragma unroll
    for (int off = 32; off > 0; off >>= 1) {
        s += __shfl_down(s, off);
        ss += __shfl_down(ss, off);
    }
    __shared__ float red[8];
    const int w = tid >> 6;
    if ((tid & 63) == 0) { red[w] = s; red[4 + w] = ss; }
    __syncthreads();
    s = red[0] + red[1] + red[2] + red[3];
    ss = red[4] + red[5] + red[6] + red[7];
    const float mean = s / H;
    const float var = ss / H - mean * mean;
    const float rstd = rsqrtf(var + 1e-12f);
#pragma unroll
    for (int i = 0; i < 4; ++i) {
        int idx = (i * 256 + tid) * 4;
        float4 wv = *(const float4*)(nw + idx);
        float4 bv = *(const float4*)(nb + idx);
        float4 r;
        r.x = v[i * 4 + 0]; r.y = v[i * 4 + 1]; r.z = v[i * 4 + 2]; r.w = v[i * 4 + 3];
        *(float4*)(resadd + base + idx) = r;
        ushort4 o;
        o.x = f2bf((r.x - mean) * rstd * wv.x + bv.x);
        o.y = f2bf((r.y - mean) * rstd * wv.y + bv.y);
        o.z = f2bf((r.z - mean) * rstd * wv.z + bv.z);
        o.w = f2bf((r.w - mean) * rstd * wv.w + bv.w);
        *(ushort4*)(lnout + base + idx) = o;
    }
}

// ---------------- fp32 -> bf16 weight cast ----------------
__global__ __launch_bounds__(256)
void cast_w(const float* __restrict__ w, unsigned short* __restrict__ o, long long n4) {
    long long i = (long long)blockIdx.x * 256 + threadIdx.x;
    if (i >= n4) return;
    float4 f = *(const float4*)(w + i * 4);
    ushort4 u;
    u.x = f2bf(f.x); u.y = f2bf(f.y); u.z = f2bf(f.z); u.w = f2bf(f.w);
    *(ushort4*)(o + i * 4) = u;
}

// ---------------- 256x256 bf16 GEMM, C = A * B^T, counted-vmcnt pipeline --
// A [M,K] bf16 row-major, B [N,K] bf16 row-major.
// 512 threads = 8 waves (2M x 4N), per-wave output 128x64.
// LDS: 2 slots x (A 256x64 + B 256x64) bf16 = 128 KiB, 1 block/CU.
// Iteration t: issue stage(t+1 -> slot^1), s_waitcnt vmcnt(8) [counted],
// s_barrier, 4 quadrant phases (ds_read + 16 MFMA each, setprio-wrapped),
// s_barrier. Staging writes never touch the slot being read (race-free by
// slot distance); in-flight loads are never drained mid-pipeline.
// XOR swizzle byte^=((row&7)<<4): applied on pre-swizzled global source
// (global_load_lds writes linearly) and on the ds_read address.
// EPI==0: C_bf16[m,n] = bf16(gelu(acc + bias_n[n]))
// EPI==1: C_f32 [m,n] = acc + bias_n[n] + resadd[m,n]
#define GBM 256
#define GBN 256
#define GBK 64

template <int EPI>
__global__ __launch_bounds__(512, 2)
void gemm256(const unsigned short* __restrict__ A,
             const unsigned short* __restrict__ B,
             const float* __restrict__ bias_n,
             const float* __restrict__ resadd,
             void* __restrict__ Cout,
             int M, int N, int K) {
    __shared__ unsigned short lds[2][2][GBM * GBK];  // [slot][A/B]
    const int tid = threadIdx.x;
    const int lane = tid & 63;
    const int w = tid >> 6;
    const int wr = w >> 2;   // 0..1
    const int wc = w & 3;    // 0..3

    // XCD-aware bijective block swizzle (gridDim.x % 8 == 0 for our shapes)
    const int nwg = gridDim.x;
    const int lg = (blockIdx.x & 7) * (nwg >> 3) + (blockIdx.x >> 3);
    const int nbx = N / GBN;
    const int brow = lg / nbx;
    const int bcol = lg % nbx;

    // staging: thread covers 16B at (row = c*64 + tid>>3, swizzled col)
    const int srow = tid >> 3;
    const int scol = ((((tid & 7) << 4) ^ ((srow & 7) << 4)) >> 1);  // elements
    const unsigned short* srcA = A + (size_t)(brow * GBM + srow) * K + scol;
    const unsigned short* srcB = B + (size_t)(bcol * GBN + srow) * K + scol;
    char* ldsBase = (char*)&lds[0][0][0];
    const int dOff = tid * 16;

    f32x4 acc[8][4] = {};

    const int NT = K / GBK;
    int cur = 0;

    // prologue: stage tile 0 into slot 0
#pragma unroll
    for (int c = 0; c < 4; ++c) {
        gload_lds16(srcA + (size_t)(c * 64) * K, ldsBase + c * 8192 + dOff);
        gload_lds16(srcB + (size_t)(c * 64) * K, ldsBase + 32768 + c * 8192 + dOff);
    }

    const int lrow = lane & 15;
    const int lswz = (lane & 7) << 4;
    const int lkx = (lane >> 4) << 4;

    for (int t = 0; t < NT; ++t) {
        if (t + 1 < NT) {
            const int kt = (t + 1) * GBK;
            char* dst = ldsBase + (cur ^ 1) * 65536;
#pragma unroll
            for (int c = 0; c < 4; ++c) {
                gload_lds16(srcA + (size_t)(c * 64) * K + kt, dst + c * 8192 + dOff);
                gload_lds16(srcB + (size_t)(c * 64) * K + kt, dst + 32768 + c * 8192 + dOff);
            }
            asm volatile("s_waitcnt vmcnt(8)" ::: "memory");  // tile t resident; t+1 in flight
        } else {
            asm volatile("s_waitcnt vmcnt(0)" ::: "memory");
        }
        __builtin_amdgcn_s_barrier();
        __builtin_amdgcn_sched_barrier(0);

        const char* sA = (const char*)ldsBase + cur * 65536;
        const char* sB = sA + 32768;
        bf16x8 bq[4][2];
#pragma unroll
        for (int q = 0; q < 4; ++q) {
            if (q == 0) {
#pragma unroll
                for (int ni = 0; ni < 4; ++ni)
#pragma unroll
                    for (int kk = 0; kk < 2; ++kk)
                        bq[ni][kk] = *(const bf16x8*)(sB
                            + ((wc * 64 + ni * 16 + lrow) << 7)
                            + (((kk << 6) | lkx) ^ lswz));
            }
            bf16x8 aq[2][2];
#pragma unroll
            for (int m2 = 0; m2 < 2; ++m2)
#pragma unroll
                for (int kk = 0; kk < 2; ++kk)
                    aq[m2][kk] = *(const bf16x8*)(sA
                        + ((wr * 128 + (q * 2 + m2) * 16 + lrow) << 7)
                        + (((kk << 6) | lkx) ^ lswz));
            __builtin_amdgcn_s_setprio(1);
#pragma unroll
            for (int m2 = 0; m2 < 2; ++m2)
#pragma unroll
                for (int ni = 0; ni < 4; ++ni)
#pragma unroll
                    for (int kk = 0; kk < 2; ++kk)
                        acc[q * 2 + m2][ni] = __builtin_amdgcn_mfma_f32_16x16x32_bf16(
                            aq[m2][kk], bq[ni][kk], acc[q * 2 + m2][ni], 0, 0, 0);
            __builtin_amdgcn_s_setprio(0);
        }
        __builtin_amdgcn_sched_barrier(0);
        __builtin_amdgcn_s_barrier();
        cur ^= 1;
    }

    // epilogue: C/D layout col = lane&15, row = (lane>>4)*4 + j
    const int c0 = bcol * GBN + wc * 64 + lrow;
    const int r0 = brow * GBM + wr * 128 + (lane >> 4) * 4;
#pragma unroll
    for (int mi = 0; mi < 8; ++mi) {
#pragma unroll
        for (int j = 0; j < 4; ++j) {
            const int row = r0 + mi * 16 + j;
#pragma unroll
            for (int ni = 0; ni < 4; ++ni) {
                const int col = c0 + ni * 16;
                float x = acc[mi][ni][j] + bias_n[col];
                if (EPI == 0) {
                    ((unsigned short*)Cout)[(size_t)row * N + col] = f2bf(gelu_tanh(x));
                } else {
                    const size_t off = (size_t)row * N + col;
                    ((float*)Cout)[off] = x + resadd[off];
                }
            }
        }
    }
}

extern "C" void kernel_launch(void* const* d_in, const int* in_sizes, int n_in,
                              void* d_out, int out_size, void* d_ws, size_t ws_size,
                              hipStream_t stream) {
    const float* input    = (const float*)d_in[0];
    const float* residual = (const float*)d_in[1];
    const float* bias     = (const float*)d_in[2];
    const float* attn_nw  = (const float*)d_in[3];
    const float* attn_nb  = (const float*)d_in[4];
    const float* inter_w  = (const float*)d_in[5];
    const float* inter_b  = (const float*)d_in[6];
    const float* output_w = (const float*)d_in[7];
    const float* output_b = (const float*)d_in[8];

    const int H = in_sizes[3];            // 4096
    const int I = in_sizes[6];            // 16384
    const int T = in_sizes[0] / H;        // B*S = 4096

    // workspace: resadd fp32 [T,H] | ln bf16 [T,H] | w1 bf16 [I,H] | w2 bf16 [H,I] | act bf16 [T,I]
    char* ws = (char*)d_ws;
    float* resadd      = (float*)ws;
    unsigned short* ln = (unsigned short*)(ws + (size_t)T * H * 4);
    unsigned short* w1 = (unsigned short*)((char*)ln + (size_t)T * H * 2);
    unsigned short* w2 = w1 + (size_t)I * H;
    unsigned short* act = w2 + (size_t)H * I;

    fused_add_ln<<<T, 256, 0, stream>>>(input, residual, bias, attn_nw, attn_nb,
                                        resadd, ln, H);

    {
        long long n4 = (long long)I * H / 4;
        int blocks = (int)((n4 + 255) / 256);
        cast_w<<<blocks, 256, 0, stream>>>(inter_w, w1, n4);
        cast_w<<<blocks, 256, 0, stream>>>(output_w, w2, n4);
    }

    // GEMM1: act = gelu(ln @ inter_w^T + inter_b)   [T,I]
    {
        dim3 grid((T / GBM) * (I / GBN));
        gemm256<0><<<grid, 512, 0, stream>>>(ln, w1, inter_b, nullptr, act, T, I, H);
    }

    // GEMM2: out = act @ output_w^T + output_b + resadd   [T,H]
    {
        dim3 grid((T / GBM) * (H / GBN));
        gemm256<1><<<grid, 512, 0, stream>>>(act, w2, output_b, resadd, d_out, T, H, I);
    }
}